// Round 10
// baseline (915.793 us; speedup 1.0000x reference)
//
#include <hip/hip_runtime.h>

// DGraphDTA r10: register-blocked node GEMM (128x64 tile, 8x4/thread) ->
// FMA:LDS cycle ratio 1.3->1.8, half the barriers per FLOP (r9 pro-L3 gemm:
// 100us @ VALUBusy 48%). Everything else = r9.

static inline int cdiv(int a, int b) { return (a + b - 1) / b; }

// ---------------- CSR build ----------------

__global__ void deg_kernel(const int* __restrict__ dst, int* __restrict__ deg, int E) {
    int t = blockIdx.x * blockDim.x + threadIdx.x;
    if (t < E) atomicAdd(&deg[dst[t]], 1);
}

__global__ void norm_kernel(const int* __restrict__ deg, float* __restrict__ norm, int N) {
    int t = blockIdx.x * blockDim.x + threadIdx.x;
    if (t < N) norm[t] = rsqrtf((float)deg[t] + 1.0f);
}

__global__ void alloc_rows_kernel(const int* __restrict__ deg, int* __restrict__ row_start,
                                  int* __restrict__ fill_cur, int* __restrict__ cursor, int N) {
    int t = blockIdx.x * blockDim.x + threadIdx.x;
    if (t >= N) return;
    int s = atomicAdd(cursor, deg[t]);
    row_start[t] = s;
    fill_cur[t] = s;
}

__global__ void fill_kernel(const int* __restrict__ src, const int* __restrict__ dst,
                            int* __restrict__ fill_cur, int* __restrict__ edge_src, int E) {
    int t = blockIdx.x * blockDim.x + threadIdx.x;
    if (t >= E) return;
    int p = atomicAdd(&fill_cur[dst[t]], 1);
    edge_src[p] = src[t];
}

// ---------------- vectorized gather-aggregate (norm fused) ----------------

__device__ __forceinline__ float4 vmad(float s, float4 a, float4 b) {
    return make_float4(fmaf(s, a.x, b.x), fmaf(s, a.y, b.y), fmaf(s, a.z, b.z), fmaf(s, a.w, b.w));
}
__device__ __forceinline__ float2 vmad(float s, float2 a, float2 b) {
    return make_float2(fmaf(s, a.x, b.x), fmaf(s, a.y, b.y));
}
__device__ __forceinline__ float4 vmul(float s, float4 a) {
    return make_float4(s * a.x, s * a.y, s * a.z, s * a.w);
}
__device__ __forceinline__ float2 vmul(float s, float2 a) {
    return make_float2(s * a.x, s * a.y);
}

template <typename VT>
__global__ __launch_bounds__(256) void gather_agg_kernel(
    const float* __restrict__ x, const float* __restrict__ norm,
    const int* __restrict__ row_start, const int* __restrict__ deg,
    const int* __restrict__ edge_src, float* __restrict__ agg, int N, int Fv)
{
    int t = blockIdx.x * blockDim.x + threadIdx.x;
    if (t >= N * Fv) return;
    int n = t / Fv;
    int jv = t - n * Fv;
    const VT* xv = reinterpret_cast<const VT*>(x);
    VT* aggv = reinterpret_cast<VT*>(agg);

    VT acc = vmul(norm[n], xv[(size_t)n * Fv + jv]);
    int rs = row_start[n];
    int d = deg[n];
    const int* es = edge_src + rs;
    int i = 0;
    for (; i + 2 <= d; i += 2) {
        int s0 = es[i], s1 = es[i + 1];
        float n0 = norm[s0], n1 = norm[s1];
        VT v0 = xv[(size_t)s0 * Fv + jv];
        VT v1 = xv[(size_t)s1 * Fv + jv];
        acc = vmad(n0, v0, acc);
        acc = vmad(n1, v1, acc);
    }
    if (i < d) {
        int s0 = es[i];
        acc = vmad(norm[s0], xv[(size_t)s0 * Fv + jv], acc);
    }
    aggv[t] = acc;
}

// ---------------- tiled GEMM: 128x64 tile, 8x4 per thread ----------------
template <bool RELU, bool SCALE>
__global__ __launch_bounds__(256) void gemm_kernel(
    const float* __restrict__ X, const float* __restrict__ W,
    const float* __restrict__ bias, const float* __restrict__ scale,
    float* __restrict__ out, int M, int K, int N, int out_stride, int out_off)
{
    constexpr int BM = 128, BN = 64, BK = 16, LDA = BM + 4;
    __shared__ __align__(16) float As[BK * LDA];  // As[k][m] transposed, 8.4 KB
    __shared__ __align__(16) float Bs[BK * BN];   // Bs[k][n], 4 KB
    const int tid = threadIdx.x;
    const int row0 = blockIdx.y * BM, col0 = blockIdx.x * BN;
    const int tx = tid & 15, ty = tid >> 4;

    float acc[8][4] = {};

    const int a_lk = tid & 15;   // k
    const int a_r0 = tid >> 4;   // row base (8 passes, stride 16)
    const int b_lc = tid & 63;   // col
    const int b_lk = tid >> 6;   // 0..3

    for (int k0 = 0; k0 < K; k0 += BK) {
#pragma unroll
        for (int p = 0; p < 8; ++p) {
            int r = a_r0 + p * 16;
            int gm = row0 + r, gk = k0 + a_lk;
            As[a_lk * LDA + r] = (gm < M && gk < K) ? X[(size_t)gm * K + gk] : 0.0f;
        }
#pragma unroll
        for (int p = 0; p < 4; ++p) {
            int kk = b_lk + p * 4;
            int gk = k0 + kk, gn = col0 + b_lc;
            Bs[kk * BN + b_lc] = (gk < K && gn < N) ? W[(size_t)gk * N + gn] : 0.0f;
        }
        __syncthreads();
#pragma unroll
        for (int k = 0; k < BK; ++k) {
            const float4 a0 = *reinterpret_cast<const float4*>(&As[k * LDA + ty * 8]);
            const float4 a1 = *reinterpret_cast<const float4*>(&As[k * LDA + ty * 8 + 4]);
            const float4 b4 = *reinterpret_cast<const float4*>(&Bs[k * BN + tx * 4]);
            const float av[8] = {a0.x, a0.y, a0.z, a0.w, a1.x, a1.y, a1.z, a1.w};
            const float bv[4] = {b4.x, b4.y, b4.z, b4.w};
#pragma unroll
            for (int i = 0; i < 8; ++i)
#pragma unroll
                for (int j = 0; j < 4; ++j)
                    acc[i][j] = fmaf(av[i], bv[j], acc[i][j]);
        }
        __syncthreads();
    }

#pragma unroll
    for (int i = 0; i < 8; ++i) {
        int gm = row0 + ty * 8 + i;
        if (gm >= M) continue;
        float sc = SCALE ? scale[gm] : 1.0f;
#pragma unroll
        for (int j = 0; j < 4; ++j) {
            int gn = col0 + tx * 4 + j;
            if (gn >= N) continue;
            float v = acc[i][j];
            if (SCALE) v *= sc;
            v += bias[gn];
            if (RELU) v = fmaxf(v, 0.0f);
            out[(size_t)gm * out_stride + out_off + gn] = v;
        }
    }
}

// ---------------- FC kernel v3 (M = 256): M-reuse + deep split-K ----------------
template <bool RELU, int MR, int JT>
__global__ __launch_bounds__(256) void fc_kernel(
    const float* __restrict__ X, const float* __restrict__ W,
    const float* __restrict__ bias, float* __restrict__ out,
    int K, int N, int out_stride, int out_off)
{
    constexpr int TJ = JT / 4;
    constexpr int SK = 256 / TJ;
    extern __shared__ float smem[];   // Xs[MR*K] + red[SK*MR*JT]
    float* Xs = smem;
    float* red = smem + MR * K;

    const int tid = threadIdx.x;
    const int m0 = blockIdx.y * MR;
    const int j0 = blockIdx.x * JT;

    for (int idx = tid; idx < MR * K; idx += 256) {
        int r = idx / K, k = idx - r * K;
        Xs[idx] = X[(size_t)(m0 + r) * K + k];
    }
    __syncthreads();

    const int tj = tid % TJ;
    const int s  = tid / TJ;
    const int chunk = (K + SK - 1) / SK;
    const int kb = s * chunk;
    const int ke = min(K, kb + chunk);

    const float4* w4 = reinterpret_cast<const float4*>(W + j0) + tj;
    const int wstride = N >> 2;

    float4 acc[MR];
#pragma unroll
    for (int r = 0; r < MR; ++r) acc[r] = make_float4(0.f, 0.f, 0.f, 0.f);
    for (int k = kb; k < ke; ++k) {
        float4 w = w4[(size_t)k * wstride];
#pragma unroll
        for (int r = 0; r < MR; ++r)
            acc[r] = vmad(Xs[r * K + k], w, acc[r]);
    }
#pragma unroll
    for (int r = 0; r < MR; ++r) {
        float* rr = red + ((s * MR + r) * JT) + tj * 4;
        rr[0] = acc[r].x; rr[1] = acc[r].y; rr[2] = acc[r].z; rr[3] = acc[r].w;
    }
    __syncthreads();

    for (int o = tid; o < MR * JT; o += 256) {
        int r = o / JT, j = o - r * JT;
        float v = 0.f;
#pragma unroll
        for (int ss = 0; ss < SK; ++ss) v += red[(ss * MR + r) * JT + j];
        v += bias[j0 + j];
        if (RELU) v = fmaxf(v, 0.0f);
        out[(size_t)(m0 + r) * out_stride + out_off + j0 + j] = v;
    }
}

// final layer: one block per row, 256 threads, LDS tree reduce (K=512)
__global__ __launch_bounds__(256) void matvec_kernel(
    const float* __restrict__ X, const float* __restrict__ W,
    const float* __restrict__ bias, float* __restrict__ out, int K)
{
    __shared__ float red[256];
    const int m = blockIdx.x;
    const int tid = threadIdx.x;
    float acc = 0.f;
    for (int k = tid; k < K; k += 256) acc = fmaf(X[(size_t)m * K + k], W[k], acc);
    red[tid] = acc;
    __syncthreads();
    for (int w = 128; w >= 64; w >>= 1) {
        if (tid < w) red[tid] += red[tid + w];
        __syncthreads();
    }
    if (tid < 64) {
        float v = red[tid];
        for (int off = 32; off > 0; off >>= 1) v += __shfl_down(v, off, 64);
        if (tid == 0) out[m] = v + bias[0];
    }
}

// ---------------- pooling: boundary detection on sorted batch ----------------
__global__ void graph_starts_kernel(const int* __restrict__ batch, int* __restrict__ gstart,
                                    int N, int B) {
    int t = blockIdx.x * blockDim.x + threadIdx.x;
    if (t >= N) return;
    int b = batch[t];
    int bp = (t == 0) ? -1 : batch[t - 1];
    for (int g = bp + 1; g <= b; ++g) gstart[g] = t;
    if (t == N - 1) {
        for (int g = b + 1; g <= B; ++g) gstart[g] = N;
    }
}

__global__ void pool_gather_kernel(const float* __restrict__ x, const int* __restrict__ gstart,
                                   float* __restrict__ pool, int B, int F) {
    int t = blockIdx.x * blockDim.x + threadIdx.x;
    if (t >= B * F) return;
    int g = t / F;
    int j = t - g * F;
    int s = gstart[g];
    int c = gstart[g + 1] - s;
    float acc = 0.0f;
    for (int i = 0; i < c; ++i) acc += x[(size_t)(s + i) * F + j];
    pool[t] = acc / (float)max(c, 1);
}

extern "C" void kernel_launch(void* const* d_in, const int* in_sizes, int n_in,
                              void* d_out, int out_size, void* d_ws, size_t ws_size,
                              hipStream_t stream) {
    const float* mol_x     = (const float*)d_in[0];
    const int*   mol_ei    = (const int*)  d_in[1];
    const int*   mol_batch = (const int*)  d_in[2];
    const float* pro_x     = (const float*)d_in[3];
    const int*   pro_ei    = (const int*)  d_in[4];
    const int*   pro_batch = (const int*)  d_in[5];
    const float* mw1 = (const float*)d_in[6],  * mb1 = (const float*)d_in[7];
    const float* mw2 = (const float*)d_in[8],  * mb2 = (const float*)d_in[9];
    const float* mw3 = (const float*)d_in[10], * mb3 = (const float*)d_in[11];
    const float* mfw1 = (const float*)d_in[12], * mfb1 = (const float*)d_in[13];
    const float* mfw2 = (const float*)d_in[14], * mfb2 = (const float*)d_in[15];
    const float* pw1 = (const float*)d_in[16], * pb1 = (const float*)d_in[17];
    const float* pw2 = (const float*)d_in[18], * pb2 = (const float*)d_in[19];
    const float* pw3 = (const float*)d_in[20], * pb3 = (const float*)d_in[21];
    const float* pfw1 = (const float*)d_in[22], * pfb1 = (const float*)d_in[23];
    const float* pfw2 = (const float*)d_in[24], * pfb2 = (const float*)d_in[25];
    const float* fc1w = (const float*)d_in[26], * fc1b = (const float*)d_in[27];
    const float* fc2w = (const float*)d_in[28], * fc2b = (const float*)d_in[29];
    const float* outw = (const float*)d_in[30], * outb = (const float*)d_in[31];
    float* out = (float*)d_out;

    // ---- workspace layout ----
    const int NP = 76800, EP = 768000;
    const int NM = 10240, EM = 40960;
    float* P = (float*)d_ws;                  // 76800*216
    float* Q = P + (size_t)NP * 216;          // 76800*108
    float* R = Q + (size_t)NP * 108;          // 76800*108
    float* normb = R + (size_t)NP * 108;      // 76800
    float* pool  = normb + NP;                // 256*312
    float* fcb   = pool + 256 * 312;          // 256*1024
    float* xc    = fcb + 256 * 1024;          // 256*256
    float* hb1   = xc + 256 * 256;            // 256*1024
    float* hb2   = hb1 + 256 * 1024;          // 256*512
    int* deg_i    = (int*)(hb2 + 256 * 512);  // 76800
    int* row_start= deg_i + NP;               // 76800
    int* fill_cur = row_start + NP;           // 76800
    int* edge_src = fill_cur + NP;            // 768000
    int* cursor   = edge_src + EP;            // 64 (pad)
    int* gstart   = cursor + 64;              // 257

    const int BLK = 256;

    auto gcn_layer = [&](const float* xin, float* agg, float* outp,
                         const float* W, const float* b, int Nn, int Fin, int Fout) {
        if (Fin % 4 == 0) {
            int Fv = Fin / 4;
            gather_agg_kernel<float4><<<cdiv(Nn * Fv, BLK), BLK, 0, stream>>>(
                xin, normb, row_start, deg_i, edge_src, agg, Nn, Fv);
        } else {
            int Fv = Fin / 2;
            gather_agg_kernel<float2><<<cdiv(Nn * Fv, BLK), BLK, 0, stream>>>(
                xin, normb, row_start, deg_i, edge_src, agg, Nn, Fv);
        }
        dim3 grid(cdiv(Fout, 64), cdiv(Nn, 128));
        gemm_kernel<true, true><<<grid, 256, 0, stream>>>(agg, W, b, normb, outp, Nn, Fin, Fout, Fout, 0);
    };

    // FC (M=256): N>=512 -> MR=4,JT=64 ; N==128 -> MR=2,JT=32
    auto fc = [&](bool relu, const float* X, const float* W, const float* b, float* o,
                  int K, int N, int out_stride, int out_off) {
        if (N >= 512) {
            dim3 grid(N / 64, 256 / 4);
            size_t lds = (size_t)(4 * K + 16 * 4 * 64) * sizeof(float);
            if (relu) fc_kernel<true, 4, 64><<<grid, 256, lds, stream>>>(X, W, b, o, K, N, out_stride, out_off);
            else      fc_kernel<false, 4, 64><<<grid, 256, lds, stream>>>(X, W, b, o, K, N, out_stride, out_off);
        } else {  // N == 128
            dim3 grid(N / 32, 256 / 2);
            size_t lds = (size_t)(2 * K + 32 * 2 * 32) * sizeof(float);
            if (relu) fc_kernel<true, 2, 32><<<grid, 256, lds, stream>>>(X, W, b, o, K, N, out_stride, out_off);
            else      fc_kernel<false, 2, 32><<<grid, 256, lds, stream>>>(X, W, b, o, K, N, out_stride, out_off);
        }
    };

    auto branch = [&](const float* x0, const int* ei, const int* batch, int N, int E,
                      const float* W1, const float* b1, int F0, int F1,
                      const float* W2, const float* b2, int F2,
                      const float* W3, const float* b3, int F3,
                      const float* fw1, const float* fb1,
                      const float* fw2, const float* fb2, int out_off) {
        // CSR build + norm
        hipMemsetAsync(deg_i, 0, N * sizeof(int), stream);
        hipMemsetAsync(cursor, 0, sizeof(int), stream);
        deg_kernel<<<cdiv(E, BLK), BLK, 0, stream>>>(ei + E, deg_i, E);
        norm_kernel<<<cdiv(N, BLK), BLK, 0, stream>>>(deg_i, normb, N);
        alloc_rows_kernel<<<cdiv(N, BLK), BLK, 0, stream>>>(deg_i, row_start, fill_cur, cursor, N);
        fill_kernel<<<cdiv(E, BLK), BLK, 0, stream>>>(ei, ei + E, fill_cur, edge_src, E);
        graph_starts_kernel<<<cdiv(N, BLK), BLK, 0, stream>>>(batch, gstart, N, 256);

        gcn_layer(x0, Q, P, W1, b1, N, F0, F1);
        gcn_layer(P, Q, R, W2, b2, N, F1, F2);
        gcn_layer(R, Q, P, W3, b3, N, F2, F3);

        pool_gather_kernel<<<cdiv(256 * F3, BLK), BLK, 0, stream>>>(P, gstart, pool, 256, F3);
        fc(true,  pool, fw1, fb1, fcb, F3, 1024, 1024, 0);
        fc(false, fcb,  fw2, fb2, xc,  1024, 128, 256, out_off);
    };

    branch(pro_x, pro_ei, pro_batch, NP, EP,
           pw1, pb1, 54, 54, pw2, pb2, 108, pw3, pb3, 216,
           pfw1, pfb1, pfw2, pfb2, 128);
    branch(mol_x, mol_ei, mol_batch, NM, EM,
           mw1, mb1, 78, 78, mw2, mb2, 156, mw3, mb3, 312,
           mfw1, mfb1, mfw2, mfb2, 0);

    // combined head
    fc(true, xc,  fc1w, fc1b, hb1, 256, 1024, 1024, 0);
    fc(true, hb1, fc2w, fc2b, hb2, 1024, 512, 512, 0);
    matvec_kernel<<<256, 256, 0, stream>>>(hb2, outw, outb, out, 512);
}

// Round 11
// 829.527 us; speedup vs baseline: 1.1040x; 1.1040x over previous
//
#include <hip/hip_runtime.h>

// DGraphDTA r11: r9 base (64x64 gemm, proven 100us on pro L3 — r8/r10 bigger
// tiles both regressed) + padded row strides (54->56, 78->80) so ALL gathers
// are float4/16B-aligned (r9's L1/L2 gathers were float2), + norm fused into
// alloc_rows. Inputs pre-copied into padded buffers (pads zeroed).

static inline int cdiv(int a, int b) { return (a + b - 1) / b; }

// ---------------- CSR build ----------------

__global__ void deg_kernel(const int* __restrict__ dst, int* __restrict__ deg, int E) {
    int t = blockIdx.x * blockDim.x + threadIdx.x;
    if (t < E) atomicAdd(&deg[dst[t]], 1);
}

// region alloc + norm = rsqrt(deg+1) in one pass
__global__ void alloc_rows_kernel(const int* __restrict__ deg, int* __restrict__ row_start,
                                  int* __restrict__ fill_cur, int* __restrict__ cursor,
                                  float* __restrict__ norm, int N) {
    int t = blockIdx.x * blockDim.x + threadIdx.x;
    if (t >= N) return;
    int d = deg[t];
    int s = atomicAdd(cursor, d);
    row_start[t] = s;
    fill_cur[t] = s;
    norm[t] = rsqrtf((float)d + 1.0f);
}

__global__ void fill_kernel(const int* __restrict__ src, const int* __restrict__ dst,
                            int* __restrict__ fill_cur, int* __restrict__ edge_src, int E) {
    int t = blockIdx.x * blockDim.x + threadIdx.x;
    if (t >= E) return;
    int p = atomicAdd(&fill_cur[dst[t]], 1);
    edge_src[p] = src[t];
}

// pad-copy: x[N,F] -> y[N,S] with zeros in pad cols
__global__ void pad_copy_kernel(const float* __restrict__ x, float* __restrict__ y,
                                int N, int F, int S) {
    int t = blockIdx.x * blockDim.x + threadIdx.x;
    if (t >= N * S) return;
    int r = t / S, j = t - r * S;
    y[t] = (j < F) ? x[(size_t)r * F + j] : 0.0f;
}

// ---------------- float4 gather-aggregate (norm fused) ----------------

__device__ __forceinline__ float4 vmad(float s, float4 a, float4 b) {
    return make_float4(fmaf(s, a.x, b.x), fmaf(s, a.y, b.y), fmaf(s, a.z, b.z), fmaf(s, a.w, b.w));
}
__device__ __forceinline__ float4 vmul(float s, float4 a) {
    return make_float4(s * a.x, s * a.y, s * a.z, s * a.w);
}

// agg[n] = norm[n]*x[n] + sum_s norm[s]*x[s]; rows have stride 4*Fv floats.
__global__ __launch_bounds__(256) void gather_agg_kernel(
    const float* __restrict__ x, const float* __restrict__ norm,
    const int* __restrict__ row_start, const int* __restrict__ deg,
    const int* __restrict__ edge_src, float* __restrict__ agg, int N, int Fv)
{
    int t = blockIdx.x * blockDim.x + threadIdx.x;
    if (t >= N * Fv) return;
    int n = t / Fv;
    int jv = t - n * Fv;
    const float4* xv = reinterpret_cast<const float4*>(x);
    float4* aggv = reinterpret_cast<float4*>(agg);

    float4 acc = vmul(norm[n], xv[(size_t)n * Fv + jv]);
    int rs = row_start[n];
    int d = deg[n];
    const int* es = edge_src + rs;
    int i = 0;
    for (; i + 2 <= d; i += 2) {
        int s0 = es[i], s1 = es[i + 1];
        float n0 = norm[s0], n1 = norm[s1];
        float4 v0 = xv[(size_t)s0 * Fv + jv];
        float4 v1 = xv[(size_t)s1 * Fv + jv];
        acc = vmad(n0, v0, acc);
        acc = vmad(n1, v1, acc);
    }
    if (i < d) {
        int s0 = es[i];
        acc = vmad(norm[s0], xv[(size_t)s0 * Fv + jv], acc);
    }
    aggv[t] = acc;
}

// ---------------- tiled GEMM (r9 64x64/4x4 structure) + lda/out_stride ----------------
template <bool RELU, bool SCALE>
__global__ __launch_bounds__(256) void gemm_kernel(
    const float* __restrict__ X, const float* __restrict__ W,
    const float* __restrict__ bias, const float* __restrict__ scale,
    float* __restrict__ out, int M, int K, int N, int lda, int out_stride)
{
    constexpr int BM = 64, BN = 64, BK = 16, LDA = BM + 4;
    __shared__ __align__(16) float As[BK * LDA];  // As[k][m] (transposed)
    __shared__ __align__(16) float Bs[BK * BN];   // Bs[k][n]
    const int tid = threadIdx.x;
    const int row0 = blockIdx.y * BM, col0 = blockIdx.x * BN;
    const int tx = tid & 15, ty = tid >> 4;

    float acc[4][4] = {};

    const int a_lr = tid >> 4;
    const int a_lk = tid & 15;
    const int b_lc = tid & 63;
    const int b_lk = tid >> 6;

    for (int k0 = 0; k0 < K; k0 += BK) {
#pragma unroll
        for (int p = 0; p < 4; ++p) {
            int r = a_lr + p * 16;
            int gm = row0 + r, gk = k0 + a_lk;
            As[a_lk * LDA + r] = (gm < M && gk < K) ? X[(size_t)gm * lda + gk] : 0.0f;
        }
#pragma unroll
        for (int p = 0; p < 4; ++p) {
            int kk = b_lk + p * 4;
            int gk = k0 + kk, gn = col0 + b_lc;
            Bs[kk * BN + b_lc] = (gk < K && gn < N) ? W[(size_t)gk * N + gn] : 0.0f;
        }
        __syncthreads();
#pragma unroll
        for (int k = 0; k < BK; ++k) {
            const float4 a4 = *reinterpret_cast<const float4*>(&As[k * LDA + ty * 4]);
            const float4 b4 = *reinterpret_cast<const float4*>(&Bs[k * BN + tx * 4]);
            const float av[4] = {a4.x, a4.y, a4.z, a4.w};
            const float bv[4] = {b4.x, b4.y, b4.z, b4.w};
#pragma unroll
            for (int i = 0; i < 4; ++i)
#pragma unroll
                for (int j = 0; j < 4; ++j)
                    acc[i][j] = fmaf(av[i], bv[j], acc[i][j]);
        }
        __syncthreads();
    }

#pragma unroll
    for (int i = 0; i < 4; ++i) {
        int gm = row0 + ty * 4 + i;
        if (gm >= M) continue;
        float sc = SCALE ? scale[gm] : 1.0f;
#pragma unroll
        for (int j = 0; j < 4; ++j) {
            int gn = col0 + tx * 4 + j;
            if (gn >= N) continue;
            float v = acc[i][j];
            if (SCALE) v *= sc;
            v += bias[gn];
            if (RELU) v = fmaxf(v, 0.0f);
            out[(size_t)gm * out_stride + gn] = v;
        }
    }
}

// ---------------- FC kernel v3 (M = 256): M-reuse + deep split-K ----------------
template <bool RELU, int MR, int JT>
__global__ __launch_bounds__(256) void fc_kernel(
    const float* __restrict__ X, const float* __restrict__ W,
    const float* __restrict__ bias, float* __restrict__ out,
    int K, int N, int out_stride, int out_off)
{
    constexpr int TJ = JT / 4;
    constexpr int SK = 256 / TJ;
    extern __shared__ float smem[];   // Xs[MR*K] + red[SK*MR*JT]
    float* Xs = smem;
    float* red = smem + MR * K;

    const int tid = threadIdx.x;
    const int m0 = blockIdx.y * MR;
    const int j0 = blockIdx.x * JT;

    for (int idx = tid; idx < MR * K; idx += 256) {
        int r = idx / K, k = idx - r * K;
        Xs[idx] = X[(size_t)(m0 + r) * K + k];
    }
    __syncthreads();

    const int tj = tid % TJ;
    const int s  = tid / TJ;
    const int chunk = (K + SK - 1) / SK;
    const int kb = s * chunk;
    const int ke = min(K, kb + chunk);

    const float4* w4 = reinterpret_cast<const float4*>(W + j0) + tj;
    const int wstride = N >> 2;

    float4 acc[MR];
#pragma unroll
    for (int r = 0; r < MR; ++r) acc[r] = make_float4(0.f, 0.f, 0.f, 0.f);
    for (int k = kb; k < ke; ++k) {
        float4 w = w4[(size_t)k * wstride];
#pragma unroll
        for (int r = 0; r < MR; ++r)
            acc[r] = vmad(Xs[r * K + k], w, acc[r]);
    }
#pragma unroll
    for (int r = 0; r < MR; ++r) {
        float* rr = red + ((s * MR + r) * JT) + tj * 4;
        rr[0] = acc[r].x; rr[1] = acc[r].y; rr[2] = acc[r].z; rr[3] = acc[r].w;
    }
    __syncthreads();

    for (int o = tid; o < MR * JT; o += 256) {
        int r = o / JT, j = o - r * JT;
        float v = 0.f;
#pragma unroll
        for (int ss = 0; ss < SK; ++ss) v += red[(ss * MR + r) * JT + j];
        v += bias[j0 + j];
        if (RELU) v = fmaxf(v, 0.0f);
        out[(size_t)(m0 + r) * out_stride + out_off + j0 + j] = v;
    }
}

// final layer: one block per row, 256 threads, LDS tree reduce (K=512)
__global__ __launch_bounds__(256) void matvec_kernel(
    const float* __restrict__ X, const float* __restrict__ W,
    const float* __restrict__ bias, float* __restrict__ out, int K)
{
    __shared__ float red[256];
    const int m = blockIdx.x;
    const int tid = threadIdx.x;
    float acc = 0.f;
    for (int k = tid; k < K; k += 256) acc = fmaf(X[(size_t)m * K + k], W[k], acc);
    red[tid] = acc;
    __syncthreads();
    for (int w = 128; w >= 64; w >>= 1) {
        if (tid < w) red[tid] += red[tid + w];
        __syncthreads();
    }
    if (tid < 64) {
        float v = red[tid];
        for (int off = 32; off > 0; off >>= 1) v += __shfl_down(v, off, 64);
        if (tid == 0) out[m] = v + bias[0];
    }
}

// ---------------- pooling: boundary detection on sorted batch ----------------
__global__ void graph_starts_kernel(const int* __restrict__ batch, int* __restrict__ gstart,
                                    int N, int B) {
    int t = blockIdx.x * blockDim.x + threadIdx.x;
    if (t >= N) return;
    int b = batch[t];
    int bp = (t == 0) ? -1 : batch[t - 1];
    for (int g = bp + 1; g <= b; ++g) gstart[g] = t;
    if (t == N - 1) {
        for (int g = b + 1; g <= B; ++g) gstart[g] = N;
    }
}

__global__ void pool_gather_kernel(const float* __restrict__ x, const int* __restrict__ gstart,
                                   float* __restrict__ pool, int B, int F, int stride) {
    int t = blockIdx.x * blockDim.x + threadIdx.x;
    if (t >= B * F) return;
    int g = t / F;
    int j = t - g * F;
    int s = gstart[g];
    int c = gstart[g + 1] - s;
    float acc = 0.0f;
    for (int i = 0; i < c; ++i) acc += x[(size_t)(s + i) * stride + j];
    pool[t] = acc / (float)max(c, 1);
}

extern "C" void kernel_launch(void* const* d_in, const int* in_sizes, int n_in,
                              void* d_out, int out_size, void* d_ws, size_t ws_size,
                              hipStream_t stream) {
    const float* mol_x     = (const float*)d_in[0];
    const int*   mol_ei    = (const int*)  d_in[1];
    const int*   mol_batch = (const int*)  d_in[2];
    const float* pro_x     = (const float*)d_in[3];
    const int*   pro_ei    = (const int*)  d_in[4];
    const int*   pro_batch = (const int*)  d_in[5];
    const float* mw1 = (const float*)d_in[6],  * mb1 = (const float*)d_in[7];
    const float* mw2 = (const float*)d_in[8],  * mb2 = (const float*)d_in[9];
    const float* mw3 = (const float*)d_in[10], * mb3 = (const float*)d_in[11];
    const float* mfw1 = (const float*)d_in[12], * mfb1 = (const float*)d_in[13];
    const float* mfw2 = (const float*)d_in[14], * mfb2 = (const float*)d_in[15];
    const float* pw1 = (const float*)d_in[16], * pb1 = (const float*)d_in[17];
    const float* pw2 = (const float*)d_in[18], * pb2 = (const float*)d_in[19];
    const float* pw3 = (const float*)d_in[20], * pb3 = (const float*)d_in[21];
    const float* pfw1 = (const float*)d_in[22], * pfb1 = (const float*)d_in[23];
    const float* pfw2 = (const float*)d_in[24], * pfb2 = (const float*)d_in[25];
    const float* fc1w = (const float*)d_in[26], * fc1b = (const float*)d_in[27];
    const float* fc2w = (const float*)d_in[28], * fc2b = (const float*)d_in[29];
    const float* outw = (const float*)d_in[30], * outb = (const float*)d_in[31];
    float* out = (float*)d_out;

    // ---- workspace layout ----
    const int NP = 76800, EP = 768000;
    const int NM = 10240, EM = 40960;
    float* P = (float*)d_ws;                  // 76800*216
    float* Q = P + (size_t)NP * 216;          // 76800*108
    float* R = Q + (size_t)NP * 108;          // 76800*108 (also padded-input buf)
    float* normb = R + (size_t)NP * 108;      // 76800
    float* pool  = normb + NP;                // 256*312
    float* fcb   = pool + 256 * 312;          // 256*1024
    float* xc    = fcb + 256 * 1024;          // 256*256
    float* hb1   = xc + 256 * 256;            // 256*1024
    float* hb2   = hb1 + 256 * 1024;          // 256*512
    int* deg_i    = (int*)(hb2 + 256 * 512);  // 76800
    int* row_start= deg_i + NP;               // 76800
    int* fill_cur = row_start + NP;           // 76800
    int* edge_src = fill_cur + NP;            // 768000
    int* cursor   = edge_src + EP;            // 64 (pad)
    int* gstart   = cursor + 64;              // 257

    const int BLK = 256;

    // one GCN layer with padded strides: gather(xin,strideIn) -> Q ; gemm Q -> outp(strideOut)
    auto gcn_layer = [&](const float* xin, float* outp, const float* W, const float* b,
                         int Nn, int Fin, int Sin, int Fout, int Sout) {
        int Fv = Sin / 4;
        gather_agg_kernel<<<cdiv(Nn * Fv, BLK), BLK, 0, stream>>>(
            xin, normb, row_start, deg_i, edge_src, Q, Nn, Fv);
        dim3 grid(cdiv(Fout, 64), cdiv(Nn, 64));
        gemm_kernel<true, true><<<grid, 256, 0, stream>>>(Q, W, b, normb, outp, Nn, Fin, Fout, Sin, Sout);
    };

    // FC (M=256): N>=512 -> MR=4,JT=64 ; N==128 -> MR=2,JT=32
    auto fc = [&](bool relu, const float* X, const float* W, const float* b, float* o,
                  int K, int N, int out_stride, int out_off) {
        if (N >= 512) {
            dim3 grid(N / 64, 256 / 4);
            size_t lds = (size_t)(4 * K + 16 * 4 * 64) * sizeof(float);
            if (relu) fc_kernel<true, 4, 64><<<grid, 256, lds, stream>>>(X, W, b, o, K, N, out_stride, out_off);
            else      fc_kernel<false, 4, 64><<<grid, 256, lds, stream>>>(X, W, b, o, K, N, out_stride, out_off);
        } else {  // N == 128
            dim3 grid(N / 32, 256 / 2);
            size_t lds = (size_t)(2 * K + 32 * 2 * 32) * sizeof(float);
            if (relu) fc_kernel<true, 2, 32><<<grid, 256, lds, stream>>>(X, W, b, o, K, N, out_stride, out_off);
            else      fc_kernel<false, 2, 32><<<grid, 256, lds, stream>>>(X, W, b, o, K, N, out_stride, out_off);
        }
    };

    // strides: pro 54->56, 108/216 ok; mol 78->80, 156/312 ok
    auto branch = [&](const float* x0, const int* ei, const int* batch, int N, int E,
                      const float* W1, const float* b1, int F0, int S0, int F1, int S1,
                      const float* W2, const float* b2, int F2, int S2,
                      const float* W3, const float* b3, int F3, int S3,
                      const float* fw1, const float* fb1,
                      const float* fw2, const float* fb2, int out_off) {
        // CSR build + norm
        hipMemsetAsync(deg_i, 0, N * sizeof(int), stream);
        hipMemsetAsync(cursor, 0, sizeof(int), stream);
        deg_kernel<<<cdiv(E, BLK), BLK, 0, stream>>>(ei + E, deg_i, E);
        alloc_rows_kernel<<<cdiv(N, BLK), BLK, 0, stream>>>(deg_i, row_start, fill_cur, cursor, normb, N);
        fill_kernel<<<cdiv(E, BLK), BLK, 0, stream>>>(ei, ei + E, fill_cur, edge_src, E);
        graph_starts_kernel<<<cdiv(N, BLK), BLK, 0, stream>>>(batch, gstart, N, 256);

        // pad input into R (stride S0, zeros in pad)
        pad_copy_kernel<<<cdiv(N * S0, BLK), BLK, 0, stream>>>(x0, R, N, F0, S0);

        gcn_layer(R, P, W1, b1, N, F0, S0, F1, S1);   // L1: R(pad x0) -> P
        gcn_layer(P, R, W2, b2, N, F1, S1, F2, S2);   // L2: P -> R (overwrites pad x0)
        gcn_layer(R, P, W3, b3, N, F2, S2, F3, S3);   // L3: R -> P

        pool_gather_kernel<<<cdiv(256 * F3, BLK), BLK, 0, stream>>>(P, gstart, pool, 256, F3, S3);
        fc(true,  pool, fw1, fb1, fcb, F3, 1024, 1024, 0);
        fc(false, fcb,  fw2, fb2, xc,  1024, 128, 256, out_off);
    };

    branch(pro_x, pro_ei, pro_batch, NP, EP,
           pw1, pb1, 54, 56, 54, 56, pw2, pb2, 108, 108, pw3, pb3, 216, 216,
           pfw1, pfb1, pfw2, pfb2, 128);
    branch(mol_x, mol_ei, mol_batch, NM, EM,
           mw1, mb1, 78, 80, 78, 80, mw2, mb2, 156, 156, mw3, mb3, 312, 312,
           mfw1, mfb1, mfw2, mfb2, 0);

    // combined head
    fc(true, xc,  fc1w, fc1b, hb1, 256, 1024, 1024, 0);
    fc(true, hb1, fc2w, fc2b, hb2, 1024, 512, 512, 0);
    matvec_kernel<<<256, 256, 0, stream>>>(hb2, outw, outb, out, 512);
}